// Round 1
// 203.551 us; speedup vs baseline: 1.0683x; 1.0683x over previous
//
#include <hip/hip_runtime.h>
#include <hip/hip_bf16.h>
#include <cstdint>
#include <cstddef>

#define E_ 1024
#define H_ 16
#define D_ 64
#define B_ 2
#define S_ 2048
#define T_ 4096   // B_*S_
#define NQ_ 3072  // 3*E_

typedef __bf16 bf16_t;
typedef bf16_t bf16x8 __attribute__((ext_vector_type(8)));
typedef float f32x4 __attribute__((ext_vector_type(4)));

static __device__ __forceinline__ unsigned short f2bf(float f) {
    __hip_bfloat16 h = __float2bfloat16(f);
    return __builtin_bit_cast(unsigned short, h);
}
static __device__ __forceinline__ unsigned pack2(float a, float b) {
    return (unsigned)f2bf(a) | ((unsigned)f2bf(b) << 16);
}
static __device__ __forceinline__ bf16x8 ld_frag(const unsigned short* p) {
    uint4 u = *reinterpret_cast<const uint4*>(p);
    return __builtin_bit_cast(bf16x8, u);
}
// async global->LDS, 16B per lane. LDS dest must be wave-uniform-base + lane*16.
static __device__ __forceinline__ void cp16(unsigned short* lds, const unsigned short* g) {
    __builtin_amdgcn_global_load_lds(
        (const __attribute__((address_space(1))) unsigned int*)g,
        (__attribute__((address_space(3))) unsigned int*)lds, 16, 0, 0);
}
static __device__ __forceinline__ f32x4 mfma16(bf16x8 a, bf16x8 b, f32x4 c) {
    return __builtin_amdgcn_mfma_f32_16x16x32_bf16(a, b, c, 0, 0, 0);
}

// ---------------- pre-pass: fp32 -> bf16 convert ----------------
__global__ __launch_bounds__(256) void k_cvt(const float* __restrict__ in,
                                             unsigned short* __restrict__ out, int n) {
    int i = (blockIdx.x * 256 + threadIdx.x) * 4;
    if (i < n) {
        float4 v = *reinterpret_cast<const float4*>(in + i);
        uint2 o;
        o.x = pack2(v.x, v.y);
        o.y = pack2(v.z, v.w);
        *reinterpret_cast<uint2*>(out + i) = o;
    }
}

// ------------- pre-pass: transpose + convert weight: in fp32 [K][N] -> out bf16 [N][K]
__global__ __launch_bounds__(256) void k_wt(const float* __restrict__ in,
                                            unsigned short* __restrict__ out, int K, int N) {
    __shared__ float t[32][33];
    int n0 = blockIdx.x * 32, k0 = blockIdx.y * 32;
    int tx = threadIdx.x, ty = threadIdx.y; // blockDim (32,8)
    for (int j = 0; j < 4; j++) {
        int r = ty + j * 8;
        t[r][tx] = in[(size_t)(k0 + r) * N + n0 + tx];
    }
    __syncthreads();
    for (int j = 0; j < 4; j++) {
        int r = ty + j * 8;
        out[(size_t)(n0 + r) * K + k0 + tx] = f2bf(t[tx][r]);
    }
}

// ---------------- shared 128x128 GEMM core (A [M][K] bf16, Bt [N][K] bf16) ----------------
// global_load_lds staging (m97 pattern), dense LDS rows of 32 shorts (conflict-free frag reads)
static __device__ __forceinline__ void gemm_tile_128(
    const unsigned short* __restrict__ A,
    const unsigned short* __restrict__ Bt,
    int Ktot, int m0, int n0,
    unsigned short* As, unsigned short* Bs,
    f32x4 acc[4][4])
{
    const int t = threadIdx.x;
    const int w = t >> 6, lane = t & 63, lr = lane & 15, lq = lane >> 4;
    const int wm = (w >> 1) * 64, wn = (w & 1) * 64;
    for (int mt = 0; mt < 4; mt++)
        for (int nt = 0; nt < 4; nt++)
            acc[mt][nt] = (f32x4){0.f, 0.f, 0.f, 0.f};

    for (int kt = 0; kt < Ktot; kt += 32) {
        __syncthreads();
        for (int i = 0; i < 2; i++) {
            int c = t + i * 256;          // 512 16B-chunks per tile
            int row = c >> 2, kp = (c & 3) * 8;
            cp16(&As[c * 8], &A[(size_t)(m0 + row) * Ktot + kt + kp]);
        }
        for (int i = 0; i < 2; i++) {
            int c = t + i * 256;
            int row = c >> 2, kp = (c & 3) * 8;
            cp16(&Bs[c * 8], &Bt[(size_t)(n0 + row) * Ktot + kt + kp]);
        }
        __syncthreads();
        bf16x8 af[4], bfr[4];
        for (int mt = 0; mt < 4; mt++) af[mt]  = ld_frag(&As[(wm + mt * 16 + lr) * 32 + lq * 8]);
        for (int nt = 0; nt < 4; nt++) bfr[nt] = ld_frag(&Bs[(wn + nt * 16 + lr) * 32 + lq * 8]);
        for (int mt = 0; mt < 4; mt++)
            for (int nt = 0; nt < 4; nt++)
                acc[mt][nt] = mfma16(af[mt], bfr[nt], acc[mt][nt]);
    }
}

// ---------------- QKV GEMM + bias + split-heads epilogue ----------------
__global__ __launch_bounds__(256) void k_qkv(
    const unsigned short* __restrict__ Ab, const unsigned short* __restrict__ Wt,
    const float* __restrict__ bias,
    unsigned short* __restrict__ Qb, unsigned short* __restrict__ Kb,
    unsigned short* __restrict__ Vb)
{
    __shared__ __attribute__((aligned(16))) unsigned short As[128 * 32];
    __shared__ __attribute__((aligned(16))) unsigned short Bs[128 * 32];
    f32x4 acc[4][4];
    int m0 = blockIdx.x * 128, n0 = blockIdx.y * 128;
    gemm_tile_128(Ab, Wt, E_, m0, n0, As, Bs, acc);

    int t = threadIdx.x, w = t >> 6, lane = t & 63, lr = lane & 15, lq = lane >> 4;
    int wm = (w >> 1) * 64, wn = (w & 1) * 64;
    int sector = (n0 >> 10);   // whole block maps to one of q/k/v (128 | 1024)
    for (int nt = 0; nt < 4; nt++) {
        int n = n0 + wn + nt * 16 + lr;
        float bv = bias[n];
        int nn = n & 1023, h = nn >> 6, d = nn & 63;
        for (int mt = 0; mt < 4; mt++) {
            for (int i = 0; i < 4; i++) {
                int tok = m0 + wm + mt * 16 + lq * 4 + i;
                int b = tok >> 11, s = tok & 2047;
                float v = acc[mt][nt][i] + bv;
                if (sector == 0) {
                    // fold 1/sqrt(D)=0.125 AND log2(e) into Q: attn uses exp2 directly
                    Qb[(((size_t)(b * H_ + h) * S_ + s) << 6) + d] = f2bf(v * 0.18033688f);
                } else if (sector == 1) {
                    Kb[(((size_t)(b * H_ + h) * S_ + s) << 6) + d] = f2bf(v);
                } else {
                    Vb[(((size_t)(b * H_ + h) * D_ + d) << 11) + s] = f2bf(v);  // V^T [B,H,D,S]
                }
            }
        }
    }
}

// ---------------- flash attention (no causal mask; no-max softmax, deferred l) ----------------
// 2-phase pipeline: KVBLK=64, double-buffered K/V staging via global_load_lds; issue next
// tile's stage BEFORE computing current tile; ONE vmcnt(0)+barrier per tile. LDS = 40KB ->
// 4 blocks/CU (grid = 1024 = exactly 4/CU resident). S^T orientation: S^T = K * Q^T; lane
// holds 4 consecutive keys -> packed b64 P-writes into wave-private Ps (no barrier needed).
// PV: O^T = V^T * P^T. All LDS surfaces dense with segment-XOR swizzle -> conflict-free.
__global__ __launch_bounds__(256) void k_attn(
    const unsigned short* __restrict__ Qb, const unsigned short* __restrict__ Kb,
    const unsigned short* __restrict__ Vb, unsigned short* __restrict__ Ob)
{
    __shared__ __attribute__((aligned(16))) unsigned short Ks[2][64 * 64];  // [buf][key][d]
    __shared__ __attribute__((aligned(16))) unsigned short Vt[2][64 * 64];  // [buf][d][key]
    __shared__ __attribute__((aligned(16))) unsigned short Ps[4][16 * 64];  // per-wave P[q][key]

    const int t = threadIdx.x, w = t >> 6, lane = t & 63, lr = lane & 15, lq = lane >> 4;
    const int h = blockIdx.y, b = blockIdx.z;
    const size_t head = ((size_t)(b * H_ + h)) * (S_ * D_);
    const unsigned short* Qh = Qb + head;
    const unsigned short* Kh = Kb + head;
    const unsigned short* Vh = Vb + head;   // [D][S]
    const int q0 = blockIdx.x * 64 + w * 16;
    const int swz = lr & 7;

    // Q fragments (B-operand): lane holds Q[q=lr][d = kk*32 + lq*8 ..+8]; scale pre-folded
    bf16x8 qa[2];
    for (int kk = 0; kk < 2; kk++)
        qa[kk] = ld_frag(&Qh[(size_t)(q0 + lr) * 64 + kk * 32 + lq * 8]);

    f32x4 o[4];
    for (int i = 0; i < 4; i++) o[i] = (f32x4){0.f, 0.f, 0.f, 0.f};
    float lsum = 0.f;
    unsigned short* Pw = Ps[w];

    // stage one 64-key tile into buffer bb: K 64x64 (8 segs/row, XOR-swz) + V^T 64x64
    auto stage = [&](int bb, int kt) {
        for (int i = 0; i < 2; i++) {
            int c = t + i * 256;                          // 512 chunks of 16B
            int row = c >> 3, sp = c & 7, seg = sp ^ (row & 7);
            cp16(&Ks[bb][c * 8], &Kh[(size_t)(kt + row) * 64 + seg * 8]);
        }
        for (int i = 0; i < 2; i++) {
            int c = t + i * 256;
            int d = c >> 3, sp = c & 7, seg = sp ^ (d & 7);
            cp16(&Vt[bb][c * 8], &Vh[(size_t)d * S_ + kt + seg * 8]);
        }
    };

    stage(0, 0);
    asm volatile("s_waitcnt vmcnt(0)" ::: "memory");
    __syncthreads();

    int cur = 0;
    for (int kt = 0; kt < S_; kt += 64) {
        // issue next tile's loads first -- latency hides under this tile's compute
        if (kt + 64 < S_) stage(cur ^ 1, kt + 64);

        const unsigned short* Kc = Ks[cur];
        const unsigned short* Vc = Vt[cur];

        // scores: S^T[key][q], 4 key-tiles of 16; lane reg r holds key = tau*16+lq*4+r, q = lr
        float pexp[4][4];
        for (int tau = 0; tau < 4; tau++) {
            f32x4 z = (f32x4){0.f, 0.f, 0.f, 0.f};
            bf16x8 kf0 = ld_frag(&Kc[(tau * 16 + lr) * 64 + ((0 + lq) ^ swz) * 8]);
            bf16x8 kf1 = ld_frag(&Kc[(tau * 16 + lr) * 64 + ((4 + lq) ^ swz) * 8]);
            __builtin_amdgcn_s_setprio(1);
            z = mfma16(kf0, qa[0], z);
            z = mfma16(kf1, qa[1], z);
            __builtin_amdgcn_s_setprio(0);
            for (int r = 0; r < 4; r++) {
                float p = __builtin_amdgcn_exp2f(z[r]);  // log2e folded into Q scale
                pexp[tau][r] = p;
                lsum += p;
            }
        }
        // P[q=lr][key]: 4 consecutive keys per lane -> one b64 per tau
        for (int tau = 0; tau < 4; tau++) {
            uint2 pk;
            pk.x = pack2(pexp[tau][0], pexp[tau][1]);
            pk.y = pack2(pexp[tau][2], pexp[tau][3]);
            int seg = (tau * 2 + (lq >> 1)) ^ swz;
            *reinterpret_cast<uint2*>(&Pw[lr * 64 + seg * 8 + (lq & 1) * 4]) = pk;
        }
        // PV: O^T[d][q] += V^T * P^T ; A = Vt rows, B = P rows (wave-private, no barrier)
        for (int kk = 0; kk < 2; kk++) {
            bf16x8 pf = ld_frag(&Pw[lr * 64 + ((kk * 4 + lq) ^ swz) * 8]);
            __builtin_amdgcn_s_setprio(1);
            for (int t2 = 0; t2 < 4; t2++) {
                bf16x8 vf = ld_frag(&Vc[(t2 * 16 + lr) * 64 + ((kk * 4 + lq) ^ swz) * 8]);
                o[t2] = mfma16(vf, pf, o[t2]);
            }
            __builtin_amdgcn_s_setprio(0);
        }

        // drain next-tile stage (hidden under compute) + single barrier per tile
        asm volatile("s_waitcnt vmcnt(0)" ::: "memory");
        __syncthreads();
        cur ^= 1;
    }

    // deferred softmax denominator: reduce across the 4 lq groups
    lsum += __shfl_xor(lsum, 16, 64);
    lsum += __shfl_xor(lsum, 32, 64);
    float inv = 1.0f / lsum;

    // epilogue: lane holds O^T[d = t2*16+lq*4+r][q = lr] -> Ob[(b,s)][h*64+d], b64 stores
    int s = q0 + lr;
    size_t rowoff = ((size_t)(b * S_ + s)) * E_ + h * 64;
    for (int t2 = 0; t2 < 4; t2++) {
        uint2 pk;
        pk.x = pack2(o[t2][0] * inv, o[t2][1] * inv);
        pk.y = pack2(o[t2][2] * inv, o[t2][3] * inv);
        *reinterpret_cast<uint2*>(&Ob[rowoff + t2 * 16 + lq * 4]) = pk;
    }
}

// ---------------- output projection + bias -> fp32 out ----------------
__global__ __launch_bounds__(256) void k_proj(
    const unsigned short* __restrict__ Ab, const unsigned short* __restrict__ Wt,
    const float* __restrict__ bias, float* __restrict__ out)
{
    __shared__ __attribute__((aligned(16))) unsigned short As[128 * 32];
    __shared__ __attribute__((aligned(16))) unsigned short Bs[128 * 32];
    f32x4 acc[4][4];
    int m0 = blockIdx.x * 128, n0 = blockIdx.y * 128;
    gemm_tile_128(Ab, Wt, E_, m0, n0, As, Bs, acc);

    int t = threadIdx.x, w = t >> 6, lane = t & 63, lr = lane & 15, lq = lane >> 4;
    int wm = (w >> 1) * 64, wn = (w & 1) * 64;
    for (int nt = 0; nt < 4; nt++) {
        int n = n0 + wn + nt * 16 + lr;
        float bv = bias[n];
        for (int mt = 0; mt < 4; mt++)
            for (int i = 0; i < 4; i++) {
                int tok = m0 + wm + mt * 16 + lq * 4 + i;
                out[(size_t)tok * E_ + n] = acc[mt][nt][i] + bv;
            }
    }
}

extern "C" void kernel_launch(void* const* d_in, const int* in_sizes, int n_in,
                              void* d_out, int out_size, void* d_ws, size_t ws_size,
                              hipStream_t stream) {
    const float* hs = (const float*)d_in[0];   // [2,2048,1024]
    const float* w1 = (const float*)d_in[1];   // [1024,3072]
    const float* b1 = (const float*)d_in[2];   // [3072]
    const float* w2 = (const float*)d_in[3];   // [1024,1024]
    const float* b2 = (const float*)d_in[4];   // [1024]
    float* out = (float*)d_out;

    char* ws = (char*)d_ws;
    unsigned short* hb  = (unsigned short*)(ws);                       // 8 MB hidden bf16
    unsigned short* w1t = (unsigned short*)(ws + (size_t)( 8 << 20));  // 6 MB W_qkv^T bf16
    unsigned short* w2t = (unsigned short*)(ws + (size_t)(14 << 20));  // 2 MB W_proj^T bf16
    unsigned short* Qb  = (unsigned short*)(ws + (size_t)(16 << 20));  // 8 MB [B,H,S,D] (pre-scaled)
    unsigned short* Kb  = (unsigned short*)(ws + (size_t)(24 << 20));  // 8 MB [B,H,S,D]
    unsigned short* Vb  = (unsigned short*)(ws + (size_t)(32 << 20));  // 8 MB [B,H,D,S]
    unsigned short* Ao  = (unsigned short*)(ws + (size_t)(40 << 20));  // 8 MB [T,E]

    k_cvt<<<dim3(T_ * E_ / 1024), dim3(256), 0, stream>>>(hs, hb, T_ * E_);
    k_wt<<<dim3(NQ_ / 32, E_ / 32), dim3(32, 8), 0, stream>>>(w1, w1t, E_, NQ_);
    k_wt<<<dim3(E_ / 32, E_ / 32), dim3(32, 8), 0, stream>>>(w2, w2t, E_, E_);
    k_qkv<<<dim3(T_ / 128, NQ_ / 128), dim3(256), 0, stream>>>(hb, w1t, b1, Qb, Kb, Vb);
    k_attn<<<dim3(S_ / 64, H_, B_), dim3(256), 0, stream>>>(Qb, Kb, Vb, Ao);
    k_proj<<<dim3(T_ / 128, E_ / 128), dim3(256), 0, stream>>>(Ao, w2t, b2, out);
}

// Round 2
// 194.266 us; speedup vs baseline: 1.1193x; 1.0478x over previous
//
#include <hip/hip_runtime.h>
#include <hip/hip_bf16.h>
#include <cstdint>
#include <cstddef>

#define E_ 1024
#define H_ 16
#define D_ 64
#define B_ 2
#define S_ 2048
#define T_ 4096   // B_*S_
#define NQ_ 3072  // 3*E_

typedef __bf16 bf16_t;
typedef bf16_t bf16x8 __attribute__((ext_vector_type(8)));
typedef float f32x4 __attribute__((ext_vector_type(4)));

static __device__ __forceinline__ unsigned short f2bf(float f) {
    __hip_bfloat16 h = __float2bfloat16(f);
    return __builtin_bit_cast(unsigned short, h);
}
static __device__ __forceinline__ unsigned pack2(float a, float b) {
    return (unsigned)f2bf(a) | ((unsigned)f2bf(b) << 16);
}
// HW packed f32->bf16 (RNE), 1 instruction. T12 recipe (no builtin on gfx950).
static __device__ __forceinline__ unsigned cvt_pk(float a, float b) {
    unsigned r;
    asm("v_cvt_pk_bf16_f32 %0, %1, %2" : "=v"(r) : "v"(a), "v"(b));
    return r;
}
static __device__ __forceinline__ bf16x8 ld_frag(const unsigned short* p) {
    uint4 u = *reinterpret_cast<const uint4*>(p);
    return __builtin_bit_cast(bf16x8, u);
}
// async global->LDS, 16B per lane. LDS dest must be wave-uniform-base + lane*16.
static __device__ __forceinline__ void cp16(unsigned short* lds, const unsigned short* g) {
    __builtin_amdgcn_global_load_lds(
        (const __attribute__((address_space(1))) unsigned int*)g,
        (__attribute__((address_space(3))) unsigned int*)lds, 16, 0, 0);
}
static __device__ __forceinline__ f32x4 mfma16(bf16x8 a, bf16x8 b, f32x4 c) {
    return __builtin_amdgcn_mfma_f32_16x16x32_bf16(a, b, c, 0, 0, 0);
}

// ---------------- pre-pass: fp32 -> bf16 convert ----------------
__global__ __launch_bounds__(256) void k_cvt(const float* __restrict__ in,
                                             unsigned short* __restrict__ out, int n) {
    int i = (blockIdx.x * 256 + threadIdx.x) * 4;
    if (i < n) {
        float4 v = *reinterpret_cast<const float4*>(in + i);
        uint2 o;
        o.x = pack2(v.x, v.y);
        o.y = pack2(v.z, v.w);
        *reinterpret_cast<uint2*>(out + i) = o;
    }
}

// ------------- pre-pass: transpose + convert weight: in fp32 [K][N] -> out bf16 [N][K]
__global__ __launch_bounds__(256) void k_wt(const float* __restrict__ in,
                                            unsigned short* __restrict__ out, int K, int N) {
    __shared__ float t[32][33];
    int n0 = blockIdx.x * 32, k0 = blockIdx.y * 32;
    int tx = threadIdx.x, ty = threadIdx.y; // blockDim (32,8)
    for (int j = 0; j < 4; j++) {
        int r = ty + j * 8;
        t[r][tx] = in[(size_t)(k0 + r) * N + n0 + tx];
    }
    __syncthreads();
    for (int j = 0; j < 4; j++) {
        int r = ty + j * 8;
        out[(size_t)(n0 + r) * K + k0 + tx] = f2bf(t[tx][r]);
    }
}

// ---------------- shared 128x128 GEMM core (A [M][K] bf16, Bt [N][K] bf16) ----------------
// global_load_lds staging (m97 pattern), dense LDS rows of 32 shorts (conflict-free frag reads)
static __device__ __forceinline__ void gemm_tile_128(
    const unsigned short* __restrict__ A,
    const unsigned short* __restrict__ Bt,
    int Ktot, int m0, int n0,
    unsigned short* As, unsigned short* Bs,
    f32x4 acc[4][4])
{
    const int t = threadIdx.x;
    const int w = t >> 6, lane = t & 63, lr = lane & 15, lq = lane >> 4;
    const int wm = (w >> 1) * 64, wn = (w & 1) * 64;
    for (int mt = 0; mt < 4; mt++)
        for (int nt = 0; nt < 4; nt++)
            acc[mt][nt] = (f32x4){0.f, 0.f, 0.f, 0.f};

    for (int kt = 0; kt < Ktot; kt += 32) {
        __syncthreads();
        for (int i = 0; i < 2; i++) {
            int c = t + i * 256;          // 512 16B-chunks per tile
            int row = c >> 2, kp = (c & 3) * 8;
            cp16(&As[c * 8], &A[(size_t)(m0 + row) * Ktot + kt + kp]);
        }
        for (int i = 0; i < 2; i++) {
            int c = t + i * 256;
            int row = c >> 2, kp = (c & 3) * 8;
            cp16(&Bs[c * 8], &Bt[(size_t)(n0 + row) * Ktot + kt + kp]);
        }
        __syncthreads();
        bf16x8 af[4], bfr[4];
        for (int mt = 0; mt < 4; mt++) af[mt]  = ld_frag(&As[(wm + mt * 16 + lr) * 32 + lq * 8]);
        for (int nt = 0; nt < 4; nt++) bfr[nt] = ld_frag(&Bs[(wn + nt * 16 + lr) * 32 + lq * 8]);
        for (int mt = 0; mt < 4; mt++)
            for (int nt = 0; nt < 4; nt++)
                acc[mt][nt] = mfma16(af[mt], bfr[nt], acc[mt][nt]);
    }
}

// ---------------- QKV GEMM + bias + split-heads epilogue ----------------
__global__ __launch_bounds__(256) void k_qkv(
    const unsigned short* __restrict__ Ab, const unsigned short* __restrict__ Wt,
    const float* __restrict__ bias,
    unsigned short* __restrict__ Qb, unsigned short* __restrict__ Kb,
    unsigned short* __restrict__ Vb)
{
    __shared__ __attribute__((aligned(16))) unsigned short As[128 * 32];
    __shared__ __attribute__((aligned(16))) unsigned short Bs[128 * 32];
    f32x4 acc[4][4];
    int m0 = blockIdx.x * 128, n0 = blockIdx.y * 128;
    gemm_tile_128(Ab, Wt, E_, m0, n0, As, Bs, acc);

    int t = threadIdx.x, w = t >> 6, lane = t & 63, lr = lane & 15, lq = lane >> 4;
    int wm = (w >> 1) * 64, wn = (w & 1) * 64;
    int sector = (n0 >> 10);   // whole block maps to one of q/k/v (128 | 1024)
    for (int nt = 0; nt < 4; nt++) {
        int n = n0 + wn + nt * 16 + lr;
        float bv = bias[n];
        int nn = n & 1023, h = nn >> 6, d = nn & 63;
        for (int mt = 0; mt < 4; mt++) {
            for (int i = 0; i < 4; i++) {
                int tok = m0 + wm + mt * 16 + lq * 4 + i;
                int b = tok >> 11, s = tok & 2047;
                float v = acc[mt][nt][i] + bv;
                if (sector == 0) {
                    // fold 1/sqrt(D)=0.125 AND log2(e) into Q: attn uses exp2 directly
                    Qb[(((size_t)(b * H_ + h) * S_ + s) << 6) + d] = f2bf(v * 0.18033688f);
                } else if (sector == 1) {
                    Kb[(((size_t)(b * H_ + h) * S_ + s) << 6) + d] = f2bf(v);
                } else {
                    Vb[(((size_t)(b * H_ + h) * D_ + d) << 11) + s] = f2bf(v);  // V^T [B,H,D,S]
                }
            }
        }
    }
}

// ---------------- flash attention (no causal mask; no-max softmax, deferred l) ----------------
// 2-phase pipeline, KVBLK=64, dbuf K/V staging. Each wave owns 32 q-rows (two 16-row halves)
// -> K/V LDS fragment reads amortized over 2x MFMA work. Block covers 128 q. LDS = 48KB,
// grid 512 = 2 blocks/CU. P-pack via HW v_cvt_pk_bf16_f32 (1 instr per pair). All LDS
// surfaces dense with segment-XOR swizzle -> conflict-free (verified pattern from r1).
__global__ __launch_bounds__(256) void k_attn(
    const unsigned short* __restrict__ Qb, const unsigned short* __restrict__ Kb,
    const unsigned short* __restrict__ Vb, unsigned short* __restrict__ Ob)
{
    __shared__ __attribute__((aligned(16))) unsigned short Ks[2][64 * 64];  // [buf][key][d]
    __shared__ __attribute__((aligned(16))) unsigned short Vt[2][64 * 64];  // [buf][d][key]
    __shared__ __attribute__((aligned(16))) unsigned short Ps[4][32 * 64];  // per-wave P[q32][key]

    const int t = threadIdx.x, w = t >> 6, lane = t & 63, lr = lane & 15, lq = lane >> 4;
    const int h = blockIdx.y, b = blockIdx.z;
    const size_t head = ((size_t)(b * H_ + h)) * (S_ * D_);
    const unsigned short* Qh = Qb + head;
    const unsigned short* Kh = Kb + head;
    const unsigned short* Vh = Vb + head;   // [D][S]
    const int q0 = blockIdx.x * 128 + w * 16;   // wave's q-halves: q0, q0+64
    const int swz = lr & 7;

    // Q fragments (B-operand): lane holds Q[q][d = kk*32 + lq*8 ..+8]; scale pre-folded
    bf16x8 qa[2][2];
    for (int qh = 0; qh < 2; qh++)
        for (int kk = 0; kk < 2; kk++)
            qa[qh][kk] = ld_frag(&Qh[(size_t)(q0 + qh * 64 + lr) * 64 + kk * 32 + lq * 8]);

    f32x4 o[2][4];
    for (int qh = 0; qh < 2; qh++)
        for (int i = 0; i < 4; i++) o[qh][i] = (f32x4){0.f, 0.f, 0.f, 0.f};
    float lsum[2] = {0.f, 0.f};
    unsigned short* Pw = Ps[w];

    // stage one 64-key tile into buffer bb: K 64x64 (8 segs/row, XOR-swz) + V^T 64x64
    auto stage = [&](int bb, int kt) {
        for (int i = 0; i < 2; i++) {
            int c = t + i * 256;                          // 512 chunks of 16B
            int row = c >> 3, sp = c & 7, seg = sp ^ (row & 7);
            cp16(&Ks[bb][c * 8], &Kh[(size_t)(kt + row) * 64 + seg * 8]);
        }
        for (int i = 0; i < 2; i++) {
            int c = t + i * 256;
            int d = c >> 3, sp = c & 7, seg = sp ^ (d & 7);
            cp16(&Vt[bb][c * 8], &Vh[(size_t)d * S_ + kt + seg * 8]);
        }
    };

    stage(0, 0);
    asm volatile("s_waitcnt vmcnt(0)" ::: "memory");
    __syncthreads();

    int cur = 0;
#pragma unroll 2
    for (int kt = 0; kt < S_; kt += 64) {
        // issue next tile's loads first -- latency hides under this tile's compute
        if (kt + 64 < S_) stage(cur ^ 1, kt + 64);

        const unsigned short* Kc = Ks[cur];
        const unsigned short* Vc = Vt[cur];

        // scores: S^T[key][q], 4 key-tiles of 16; K-frags reused across both q-halves.
        // lane reg r holds key = tau*16+lq*4+r, q = (qh*64)+lr
        for (int tau = 0; tau < 4; tau++) {
            bf16x8 kf0 = ld_frag(&Kc[(tau * 16 + lr) * 64 + ((0 + lq) ^ swz) * 8]);
            bf16x8 kf1 = ld_frag(&Kc[(tau * 16 + lr) * 64 + ((4 + lq) ^ swz) * 8]);
            for (int qh = 0; qh < 2; qh++) {
                f32x4 z = (f32x4){0.f, 0.f, 0.f, 0.f};
                __builtin_amdgcn_s_setprio(1);
                z = mfma16(kf0, qa[qh][0], z);
                z = mfma16(kf1, qa[qh][1], z);
                __builtin_amdgcn_s_setprio(0);
                float e0 = __builtin_amdgcn_exp2f(z[0]);  // log2e folded into Q scale
                float e1 = __builtin_amdgcn_exp2f(z[1]);
                float e2 = __builtin_amdgcn_exp2f(z[2]);
                float e3 = __builtin_amdgcn_exp2f(z[3]);
                lsum[qh] += (e0 + e1) + (e2 + e3);
                // P[q][key]: 4 consecutive keys per lane -> one b64 write
                uint2 pk;
                pk.x = cvt_pk(e0, e1);
                pk.y = cvt_pk(e2, e3);
                int seg = (tau * 2 + (lq >> 1)) ^ swz;
                *reinterpret_cast<uint2*>(&Pw[(qh * 16 + lr) * 64 + seg * 8 + (lq & 1) * 4]) = pk;
            }
        }
        // PV: O^T[d][q] += V^T * P^T ; A = Vt rows, B = P rows (wave-private, no barrier).
        // V-frags reused across both q-halves.
        for (int kk = 0; kk < 2; kk++) {
            bf16x8 pf0 = ld_frag(&Pw[(lr) * 64 + ((kk * 4 + lq) ^ swz) * 8]);
            bf16x8 pf1 = ld_frag(&Pw[(16 + lr) * 64 + ((kk * 4 + lq) ^ swz) * 8]);
            __builtin_amdgcn_s_setprio(1);
            for (int t2 = 0; t2 < 4; t2++) {
                bf16x8 vf = ld_frag(&Vc[(t2 * 16 + lr) * 64 + ((kk * 4 + lq) ^ swz) * 8]);
                o[0][t2] = mfma16(vf, pf0, o[0][t2]);
                o[1][t2] = mfma16(vf, pf1, o[1][t2]);
            }
            __builtin_amdgcn_s_setprio(0);
        }

        // drain next-tile stage (hidden under compute) + single barrier per tile
        asm volatile("s_waitcnt vmcnt(0)" ::: "memory");
        __syncthreads();
        cur ^= 1;
    }

    // deferred softmax denominator: reduce across the 4 lq groups; then epilogue per q-half.
    for (int qh = 0; qh < 2; qh++) {
        float ls = lsum[qh];
        ls += __shfl_xor(ls, 16, 64);
        ls += __shfl_xor(ls, 32, 64);
        float inv = 1.0f / ls;

        // lane holds O^T[d = t2*16+lq*4+r][q = lr] -> Ob[(b,s)][h*64+d], b64 stores
        int s = q0 + qh * 64 + lr;
        size_t rowoff = ((size_t)(b * S_ + s)) * E_ + h * 64;
        for (int t2 = 0; t2 < 4; t2++) {
            uint2 pk;
            pk.x = cvt_pk(o[qh][t2][0] * inv, o[qh][t2][1] * inv);
            pk.y = cvt_pk(o[qh][t2][2] * inv, o[qh][t2][3] * inv);
            *reinterpret_cast<uint2*>(&Ob[rowoff + t2 * 16 + lq * 4]) = pk;
        }
    }
}

// ---------------- output projection + bias -> fp32 out ----------------
__global__ __launch_bounds__(256) void k_proj(
    const unsigned short* __restrict__ Ab, const unsigned short* __restrict__ Wt,
    const float* __restrict__ bias, float* __restrict__ out)
{
    __shared__ __attribute__((aligned(16))) unsigned short As[128 * 32];
    __shared__ __attribute__((aligned(16))) unsigned short Bs[128 * 32];
    f32x4 acc[4][4];
    int m0 = blockIdx.x * 128, n0 = blockIdx.y * 128;
    gemm_tile_128(Ab, Wt, E_, m0, n0, As, Bs, acc);

    int t = threadIdx.x, w = t >> 6, lane = t & 63, lr = lane & 15, lq = lane >> 4;
    int wm = (w >> 1) * 64, wn = (w & 1) * 64;
    for (int nt = 0; nt < 4; nt++) {
        int n = n0 + wn + nt * 16 + lr;
        float bv = bias[n];
        for (int mt = 0; mt < 4; mt++)
            for (int i = 0; i < 4; i++) {
                int tok = m0 + wm + mt * 16 + lq * 4 + i;
                out[(size_t)tok * E_ + n] = acc[mt][nt][i] + bv;
            }
    }
}

extern "C" void kernel_launch(void* const* d_in, const int* in_sizes, int n_in,
                              void* d_out, int out_size, void* d_ws, size_t ws_size,
                              hipStream_t stream) {
    const float* hs = (const float*)d_in[0];   // [2,2048,1024]
    const float* w1 = (const float*)d_in[1];   // [1024,3072]
    const float* b1 = (const float*)d_in[2];   // [3072]
    const float* w2 = (const float*)d_in[3];   // [1024,1024]
    const float* b2 = (const float*)d_in[4];   // [1024]
    float* out = (float*)d_out;

    char* ws = (char*)d_ws;
    unsigned short* hb  = (unsigned short*)(ws);                       // 8 MB hidden bf16
    unsigned short* w1t = (unsigned short*)(ws + (size_t)( 8 << 20));  // 6 MB W_qkv^T bf16
    unsigned short* w2t = (unsigned short*)(ws + (size_t)(14 << 20));  // 2 MB W_proj^T bf16
    unsigned short* Qb  = (unsigned short*)(ws + (size_t)(16 << 20));  // 8 MB [B,H,S,D] (pre-scaled)
    unsigned short* Kb  = (unsigned short*)(ws + (size_t)(24 << 20));  // 8 MB [B,H,S,D]
    unsigned short* Vb  = (unsigned short*)(ws + (size_t)(32 << 20));  // 8 MB [B,H,D,S]
    unsigned short* Ao  = (unsigned short*)(ws + (size_t)(40 << 20));  // 8 MB [T,E]

    k_cvt<<<dim3(T_ * E_ / 1024), dim3(256), 0, stream>>>(hs, hb, T_ * E_);
    k_wt<<<dim3(NQ_ / 32, E_ / 32), dim3(32, 8), 0, stream>>>(w1, w1t, E_, NQ_);
    k_wt<<<dim3(E_ / 32, E_ / 32), dim3(32, 8), 0, stream>>>(w2, w2t, E_, E_);
    k_qkv<<<dim3(T_ / 128, NQ_ / 128), dim3(256), 0, stream>>>(hb, w1t, b1, Qb, Kb, Vb);
    k_attn<<<dim3(S_ / 128, H_, B_), dim3(256), 0, stream>>>(Qb, Kb, Vb, Ao);
    k_proj<<<dim3(T_ / 128, E_ / 128), dim3(256), 0, stream>>>(Ao, w2t, b2, out);
}

// Round 3
// 190.898 us; speedup vs baseline: 1.1391x; 1.0176x over previous
//
#include <hip/hip_runtime.h>
#include <hip/hip_bf16.h>
#include <cstdint>
#include <cstddef>

#define E_ 1024
#define H_ 16
#define D_ 64
#define B_ 2
#define S_ 2048
#define T_ 4096   // B_*S_
#define NQ_ 3072  // 3*E_

typedef __bf16 bf16_t;
typedef bf16_t bf16x8 __attribute__((ext_vector_type(8)));
typedef float f32x4 __attribute__((ext_vector_type(4)));

static __device__ __forceinline__ unsigned short f2bf(float f) {
    __hip_bfloat16 h = __float2bfloat16(f);
    return __builtin_bit_cast(unsigned short, h);
}
static __device__ __forceinline__ unsigned pack2(float a, float b) {
    return (unsigned)f2bf(a) | ((unsigned)f2bf(b) << 16);
}
// HW packed f32->bf16 (RNE), 1 instruction. T12 recipe (no builtin on gfx950).
static __device__ __forceinline__ unsigned cvt_pk(float a, float b) {
    unsigned r;
    asm("v_cvt_pk_bf16_f32 %0, %1, %2" : "=v"(r) : "v"(a), "v"(b));
    return r;
}
static __device__ __forceinline__ bf16x8 ld_frag(const unsigned short* p) {
    uint4 u = *reinterpret_cast<const uint4*>(p);
    return __builtin_bit_cast(bf16x8, u);
}
// async global->LDS, 16B per lane. LDS dest must be wave-uniform-base + lane*16.
static __device__ __forceinline__ void cp16(unsigned short* lds, const unsigned short* g) {
    __builtin_amdgcn_global_load_lds(
        (const __attribute__((address_space(1))) unsigned int*)g,
        (__attribute__((address_space(3))) unsigned int*)lds, 16, 0, 0);
}
static __device__ __forceinline__ f32x4 mfma16(bf16x8 a, bf16x8 b, f32x4 c) {
    return __builtin_amdgcn_mfma_f32_16x16x32_bf16(a, b, c, 0, 0, 0);
}

// ---------------- pre-pass: fp32 -> bf16 convert ----------------
__global__ __launch_bounds__(256) void k_cvt(const float* __restrict__ in,
                                             unsigned short* __restrict__ out, int n) {
    int i = (blockIdx.x * 256 + threadIdx.x) * 4;
    if (i < n) {
        float4 v = *reinterpret_cast<const float4*>(in + i);
        uint2 o;
        o.x = pack2(v.x, v.y);
        o.y = pack2(v.z, v.w);
        *reinterpret_cast<uint2*>(out + i) = o;
    }
}

// ------------- pre-pass: transpose + convert weight: in fp32 [K][N] -> out bf16 [N][K]
__global__ __launch_bounds__(256) void k_wt(const float* __restrict__ in,
                                            unsigned short* __restrict__ out, int K, int N) {
    __shared__ float t[32][33];
    int n0 = blockIdx.x * 32, k0 = blockIdx.y * 32;
    int tx = threadIdx.x, ty = threadIdx.y; // blockDim (32,8)
    for (int j = 0; j < 4; j++) {
        int r = ty + j * 8;
        t[r][tx] = in[(size_t)(k0 + r) * N + n0 + tx];
    }
    __syncthreads();
    for (int j = 0; j < 4; j++) {
        int r = ty + j * 8;
        out[(size_t)(n0 + r) * K + k0 + tx] = f2bf(t[tx][r]);
    }
}

// ---------------- shared 128x128 GEMM core (A [M][K] bf16, Bt [N][K] bf16) ----------------
// global_load_lds staging (m97 pattern), dense LDS rows of 32 shorts (conflict-free frag reads)
static __device__ __forceinline__ void gemm_tile_128(
    const unsigned short* __restrict__ A,
    const unsigned short* __restrict__ Bt,
    int Ktot, int m0, int n0,
    unsigned short* As, unsigned short* Bs,
    f32x4 acc[4][4])
{
    const int t = threadIdx.x;
    const int w = t >> 6, lane = t & 63, lr = lane & 15, lq = lane >> 4;
    const int wm = (w >> 1) * 64, wn = (w & 1) * 64;
    for (int mt = 0; mt < 4; mt++)
        for (int nt = 0; nt < 4; nt++)
            acc[mt][nt] = (f32x4){0.f, 0.f, 0.f, 0.f};

    for (int kt = 0; kt < Ktot; kt += 32) {
        __syncthreads();
        for (int i = 0; i < 2; i++) {
            int c = t + i * 256;          // 512 16B-chunks per tile
            int row = c >> 2, kp = (c & 3) * 8;
            cp16(&As[c * 8], &A[(size_t)(m0 + row) * Ktot + kt + kp]);
        }
        for (int i = 0; i < 2; i++) {
            int c = t + i * 256;
            int row = c >> 2, kp = (c & 3) * 8;
            cp16(&Bs[c * 8], &Bt[(size_t)(n0 + row) * Ktot + kt + kp]);
        }
        __syncthreads();
        bf16x8 af[4], bfr[4];
        for (int mt = 0; mt < 4; mt++) af[mt]  = ld_frag(&As[(wm + mt * 16 + lr) * 32 + lq * 8]);
        for (int nt = 0; nt < 4; nt++) bfr[nt] = ld_frag(&Bs[(wn + nt * 16 + lr) * 32 + lq * 8]);
        for (int mt = 0; mt < 4; mt++)
            for (int nt = 0; nt < 4; nt++)
                acc[mt][nt] = mfma16(af[mt], bfr[nt], acc[mt][nt]);
    }
}

// ---------------- QKV GEMM + bias + split-heads epilogue ----------------
__global__ __launch_bounds__(256) void k_qkv(
    const unsigned short* __restrict__ Ab, const unsigned short* __restrict__ Wt,
    const float* __restrict__ bias,
    unsigned short* __restrict__ Qb, unsigned short* __restrict__ Kb,
    unsigned short* __restrict__ Vb)
{
    __shared__ __attribute__((aligned(16))) unsigned short As[128 * 32];
    __shared__ __attribute__((aligned(16))) unsigned short Bs[128 * 32];
    f32x4 acc[4][4];
    int m0 = blockIdx.x * 128, n0 = blockIdx.y * 128;
    gemm_tile_128(Ab, Wt, E_, m0, n0, As, Bs, acc);

    int t = threadIdx.x, w = t >> 6, lane = t & 63, lr = lane & 15, lq = lane >> 4;
    int wm = (w >> 1) * 64, wn = (w & 1) * 64;
    int sector = (n0 >> 10);   // whole block maps to one of q/k/v (128 | 1024)
    for (int nt = 0; nt < 4; nt++) {
        int n = n0 + wn + nt * 16 + lr;
        float bv = bias[n];
        int nn = n & 1023, h = nn >> 6, d = nn & 63;
        for (int mt = 0; mt < 4; mt++) {
            for (int i = 0; i < 4; i++) {
                int tok = m0 + wm + mt * 16 + lq * 4 + i;
                int b = tok >> 11, s = tok & 2047;
                float v = acc[mt][nt][i] + bv;
                if (sector == 0) {
                    // fold 1/sqrt(D)=0.125 AND log2(e) into Q: attn uses exp2 directly
                    Qb[(((size_t)(b * H_ + h) * S_ + s) << 6) + d] = f2bf(v * 0.18033688f);
                } else if (sector == 1) {
                    Kb[(((size_t)(b * H_ + h) * S_ + s) << 6) + d] = f2bf(v);
                } else {
                    Vb[(((size_t)(b * H_ + h) * D_ + d) << 11) + s] = f2bf(v);  // V^T [B,H,D,S]
                }
            }
        }
    }
}

// ---------------- flash attention (no causal mask; no-max softmax, deferred l) ----------------
// 2-phase pipeline, 128-key macro-tiles (2x64 sub-tiles), dbuf K/V staging -> HALF the
// barrier+drain events of the 64-key version. Each wave owns 32 q-rows (two 16-row halves);
// K/V frags amortized over 2x MFMA. LDS = 80KB; grid 512 = 2 blocks/CU (grid-limited, so
// the bigger LDS is free). All LDS surfaces dense with segment-XOR swizzle -> conflict-free.
__global__ __launch_bounds__(256) void k_attn(
    const unsigned short* __restrict__ Qb, const unsigned short* __restrict__ Kb,
    const unsigned short* __restrict__ Vb, unsigned short* __restrict__ Ob)
{
    __shared__ __attribute__((aligned(16))) unsigned short Ks[2][128 * 64];  // [buf][key][d]
    __shared__ __attribute__((aligned(16))) unsigned short Vt[2][64 * 128];  // [buf][d][key]
    __shared__ __attribute__((aligned(16))) unsigned short Ps[4][32 * 64];   // per-wave P[q32][key64]

    const int t = threadIdx.x, w = t >> 6, lane = t & 63, lr = lane & 15, lq = lane >> 4;
    const int h = blockIdx.y, b = blockIdx.z;
    const size_t head = ((size_t)(b * H_ + h)) * (S_ * D_);
    const unsigned short* Qh = Qb + head;
    const unsigned short* Kh = Kb + head;
    const unsigned short* Vh = Vb + head;   // [D][S]
    const int q0 = blockIdx.x * 128 + w * 16;   // wave's q-halves: q0, q0+64
    const int swz = lr & 7;

    // Q fragments (B-operand): lane holds Q[q][d = kk*32 + lq*8 ..+8]; scale pre-folded
    bf16x8 qa[2][2];
    for (int qh = 0; qh < 2; qh++)
        for (int kk = 0; kk < 2; kk++)
            qa[qh][kk] = ld_frag(&Qh[(size_t)(q0 + qh * 64 + lr) * 64 + kk * 32 + lq * 8]);

    f32x4 o[2][4];
    for (int qh = 0; qh < 2; qh++)
        for (int i = 0; i < 4; i++) o[qh][i] = (f32x4){0.f, 0.f, 0.f, 0.f};
    float lsum[2] = {0.f, 0.f};
    unsigned short* Pw = Ps[w];

    // stage one 128-key tile into buffer bb:
    // K 128 rows x 8 segs of 16B (seg ^ row&7); V^T 64 rows x 16 segs (low-3-bit XOR by d)
    auto stage = [&](int bb, int kt) {
        for (int i = 0; i < 4; i++) {
            int c = t + i * 256;                          // 1024 chunks of 16B
            int row = c >> 3, sp = c & 7;
            cp16(&Ks[bb][c * 8], &Kh[(size_t)(kt + row) * 64 + (sp ^ (row & 7)) * 8]);
        }
        for (int i = 0; i < 4; i++) {
            int c = t + i * 256;
            int d = c >> 4, sp = c & 15, seg = (sp & 8) | ((sp & 7) ^ (d & 7));
            cp16(&Vt[bb][c * 8], &Vh[(size_t)d * S_ + kt + seg * 8]);
        }
    };

    stage(0, 0);
    asm volatile("s_waitcnt vmcnt(0)" ::: "memory");
    __syncthreads();

    int cur = 0;
#pragma unroll 2
    for (int kt = 0; kt < S_; kt += 128) {
        // issue next tile's loads first -- latency hides under this tile's compute
        if (kt + 128 < S_) stage(cur ^ 1, kt + 128);

        const unsigned short* Kc = Ks[cur];
        const unsigned short* Vc = Vt[cur];

#pragma unroll
        for (int ss = 0; ss < 2; ss++) {
            // scores: S^T[key][q], 4 key-tiles of 16 per sub-tile; K-frags reused across both
            // q-halves. lane reg r holds key = ss*64 + tau*16 + lq*4 + r, q = (qh*64)+lr
            for (int tau = 0; tau < 4; tau++) {
                int krow = ss * 64 + tau * 16 + lr;
                bf16x8 kf0 = ld_frag(&Kc[krow * 64 + ((0 + lq) ^ swz) * 8]);
                bf16x8 kf1 = ld_frag(&Kc[krow * 64 + ((4 + lq) ^ swz) * 8]);
                for (int qh = 0; qh < 2; qh++) {
                    f32x4 z = (f32x4){0.f, 0.f, 0.f, 0.f};
                    __builtin_amdgcn_s_setprio(1);
                    z = mfma16(kf0, qa[qh][0], z);
                    z = mfma16(kf1, qa[qh][1], z);
                    __builtin_amdgcn_s_setprio(0);
                    float e0 = __builtin_amdgcn_exp2f(z[0]);  // log2e folded into Q scale
                    float e1 = __builtin_amdgcn_exp2f(z[1]);
                    float e2 = __builtin_amdgcn_exp2f(z[2]);
                    float e3 = __builtin_amdgcn_exp2f(z[3]);
                    lsum[qh] += (e0 + e1) + (e2 + e3);
                    // P[q][key-within-subtile]: 4 consecutive keys -> one b64 write
                    uint2 pk;
                    pk.x = cvt_pk(e0, e1);
                    pk.y = cvt_pk(e2, e3);
                    int seg = (tau * 2 + (lq >> 1)) ^ swz;
                    *reinterpret_cast<uint2*>(&Pw[(qh * 16 + lr) * 64 + seg * 8 + (lq & 1) * 4]) = pk;
                }
            }
            // PV: O^T[d][q] += V^T * P^T ; A = Vt rows, B = P rows (wave-private, in-order DS).
            // V-frags reused across both q-halves.
            for (int kk = 0; kk < 2; kk++) {
                bf16x8 pf0 = ld_frag(&Pw[(lr) * 64 + ((kk * 4 + lq) ^ swz) * 8]);
                bf16x8 pf1 = ld_frag(&Pw[(16 + lr) * 64 + ((kk * 4 + lq) ^ swz) * 8]);
                __builtin_amdgcn_s_setprio(1);
                for (int t2 = 0; t2 < 4; t2++) {
                    int vrow = t2 * 16 + lr;
                    bf16x8 vf = ld_frag(&Vc[vrow * 128 + ((ss * 8) | ((kk * 4 + lq) ^ swz)) * 8]);
                    o[0][t2] = mfma16(vf, pf0, o[0][t2]);
                    o[1][t2] = mfma16(vf, pf1, o[1][t2]);
                }
                __builtin_amdgcn_s_setprio(0);
            }
        }

        // drain next-tile stage (hidden under compute) + single barrier per 128-key tile
        asm volatile("s_waitcnt vmcnt(0)" ::: "memory");
        __syncthreads();
        cur ^= 1;
    }

    // deferred softmax denominator: reduce across the 4 lq groups; then epilogue per q-half.
    for (int qh = 0; qh < 2; qh++) {
        float ls = lsum[qh];
        ls += __shfl_xor(ls, 16, 64);
        ls += __shfl_xor(ls, 32, 64);
        float inv = 1.0f / ls;

        // lane holds O^T[d = t2*16+lq*4+r][q = lr] -> Ob[(b,s)][h*64+d], b64 stores
        int s = q0 + qh * 64 + lr;
        size_t rowoff = ((size_t)(b * S_ + s)) * E_ + h * 64;
        for (int t2 = 0; t2 < 4; t2++) {
            uint2 pk;
            pk.x = cvt_pk(o[qh][t2][0] * inv, o[qh][t2][1] * inv);
            pk.y = cvt_pk(o[qh][t2][2] * inv, o[qh][t2][3] * inv);
            *reinterpret_cast<uint2*>(&Ob[rowoff + t2 * 16 + lq * 4]) = pk;
        }
    }
}

// ---------------- output projection + bias -> fp32 out ----------------
// 128x64 tile: grid 32x16 = 512 blocks = 2 blocks/CU (vs 1 with 128^2) -- two independent
// blocks per CU fill each other's barrier stalls. Wave owns 64x32 quadrant.
__global__ __launch_bounds__(256) void k_proj(
    const unsigned short* __restrict__ Ab, const unsigned short* __restrict__ Wt,
    const float* __restrict__ bias, float* __restrict__ out)
{
    __shared__ __attribute__((aligned(16))) unsigned short As[128 * 32];
    __shared__ __attribute__((aligned(16))) unsigned short Bs[64 * 32];
    const int t = threadIdx.x;
    const int w = t >> 6, lane = t & 63, lr = lane & 15, lq = lane >> 4;
    const int wm = (w >> 1) * 64, wn = (w & 1) * 32;
    const int m0 = blockIdx.x * 128, n0 = blockIdx.y * 64;

    f32x4 acc[4][2];
    for (int mt = 0; mt < 4; mt++)
        for (int nt = 0; nt < 2; nt++)
            acc[mt][nt] = (f32x4){0.f, 0.f, 0.f, 0.f};

    for (int kt = 0; kt < E_; kt += 32) {
        __syncthreads();
        for (int i = 0; i < 2; i++) {
            int c = t + i * 256;          // A: 512 16B-chunks
            int row = c >> 2, kp = (c & 3) * 8;
            cp16(&As[c * 8], &Ab[(size_t)(m0 + row) * E_ + kt + kp]);
        }
        {
            int c = t;                    // B: 256 16B-chunks
            int row = c >> 2, kp = (c & 3) * 8;
            cp16(&Bs[c * 8], &Wt[(size_t)(n0 + row) * E_ + kt + kp]);
        }
        __syncthreads();
        bf16x8 af[4], bfr[2];
        for (int mt = 0; mt < 4; mt++) af[mt]  = ld_frag(&As[(wm + mt * 16 + lr) * 32 + lq * 8]);
        for (int nt = 0; nt < 2; nt++) bfr[nt] = ld_frag(&Bs[(wn + nt * 16 + lr) * 32 + lq * 8]);
        for (int mt = 0; mt < 4; mt++)
            for (int nt = 0; nt < 2; nt++)
                acc[mt][nt] = mfma16(af[mt], bfr[nt], acc[mt][nt]);
    }

    for (int nt = 0; nt < 2; nt++) {
        int n = n0 + wn + nt * 16 + lr;
        float bv = bias[n];
        for (int mt = 0; mt < 4; mt++)
            for (int i = 0; i < 4; i++) {
                int tok = m0 + wm + mt * 16 + lq * 4 + i;
                out[(size_t)tok * E_ + n] = acc[mt][nt][i] + bv;
            }
    }
}

extern "C" void kernel_launch(void* const* d_in, const int* in_sizes, int n_in,
                              void* d_out, int out_size, void* d_ws, size_t ws_size,
                              hipStream_t stream) {
    const float* hs = (const float*)d_in[0];   // [2,2048,1024]
    const float* w1 = (const float*)d_in[1];   // [1024,3072]
    const float* b1 = (const float*)d_in[2];   // [3072]
    const float* w2 = (const float*)d_in[3];   // [1024,1024]
    const float* b2 = (const float*)d_in[4];   // [1024]
    float* out = (float*)d_out;

    char* ws = (char*)d_ws;
    unsigned short* hb  = (unsigned short*)(ws);                       // 8 MB hidden bf16
    unsigned short* w1t = (unsigned short*)(ws + (size_t)( 8 << 20));  // 6 MB W_qkv^T bf16
    unsigned short* w2t = (unsigned short*)(ws + (size_t)(14 << 20));  // 2 MB W_proj^T bf16
    unsigned short* Qb  = (unsigned short*)(ws + (size_t)(16 << 20));  // 8 MB [B,H,S,D] (pre-scaled)
    unsigned short* Kb  = (unsigned short*)(ws + (size_t)(24 << 20));  // 8 MB [B,H,S,D]
    unsigned short* Vb  = (unsigned short*)(ws + (size_t)(32 << 20));  // 8 MB [B,H,D,S]
    unsigned short* Ao  = (unsigned short*)(ws + (size_t)(40 << 20));  // 8 MB [T,E]

    k_cvt<<<dim3(T_ * E_ / 1024), dim3(256), 0, stream>>>(hs, hb, T_ * E_);
    k_wt<<<dim3(NQ_ / 32, E_ / 32), dim3(32, 8), 0, stream>>>(w1, w1t, E_, NQ_);
    k_wt<<<dim3(E_ / 32, E_ / 32), dim3(32, 8), 0, stream>>>(w2, w2t, E_, E_);
    k_qkv<<<dim3(T_ / 128, NQ_ / 128), dim3(256), 0, stream>>>(hb, w1t, b1, Qb, Kb, Vb);
    k_attn<<<dim3(S_ / 128, H_, B_), dim3(256), 0, stream>>>(Qb, Kb, Vb, Ao);
    k_proj<<<dim3(T_ / 128, E_ / 64), dim3(256), 0, stream>>>(Ao, w2t, b2, out);
}